// Round 4
// baseline (174.506 us; speedup 1.0000x reference)
//
#include <hip/hip_runtime.h>

typedef unsigned short u16;
typedef __bf16 bf16x8 __attribute__((ext_vector_type(8)));
typedef __bf16 bf16x4 __attribute__((ext_vector_type(4)));
typedef float f32x4 __attribute__((ext_vector_type(4)));

__device__ __forceinline__ u16 f2bf(float f) {
  __bf16 h = (__bf16)f;
  return *(u16*)&h;
}

__device__ __forceinline__ f32x4 mfma16(bf16x8 a, bf16x8 b, f32x4 c) {
  return __builtin_amdgcn_mfma_f32_16x16x32_bf16(a, b, c, 0, 0, 0);
}

__device__ __forceinline__ void async16(void* lds, const void* g) {
  __builtin_amdgcn_global_load_lds(
      (const __attribute__((address_space(1))) unsigned int*)g,
      (__attribute__((address_space(3))) unsigned int*)lds, 16, 0, 0);
}

// fold softmax scale AND log2(e) into Wq so softmax uses raw v_exp_f32 (exp2)
#define QSCALE 0.18033688011112042f  // 0.125 * log2(e)

// ---------------------------------------------------------------- prep: casts
__global__ __launch_bounds__(256) void prep_cast(
    const float* __restrict__ Wq, const float* __restrict__ Wkv,
    const float* __restrict__ Wout, const float* __restrict__ ctx,
    u16* __restrict__ Wq_b, u16* __restrict__ Wkv_b,
    u16* __restrict__ Wout_b, u16* __restrict__ ctx_b) {
  const long NWQ = 512L * 512, NWKV = 1024L * 768, NWOUT = 512L * 512, NCTX = 2048L * 768;
  const long total = NWQ + NWKV + NWOUT + NCTX;
  long stride = (long)gridDim.x * 256;
  for (long i = (long)blockIdx.x * 256 + threadIdx.x; i < total; i += stride) {
    long j = i;
    if (j < NWQ) { Wq_b[j] = f2bf(Wq[j] * QSCALE); continue; }
    j -= NWQ;
    if (j < NWKV) { Wkv_b[j] = f2bf(Wkv[j]); continue; }
    j -= NWKV;
    if (j < NWOUT) { Wout_b[j] = f2bf(Wout[j]); continue; }
    j -= NWOUT;
    ctx_b[j] = f2bf(ctx[j]);
  }
}

// ------------------------------------------------- transpose x -> xT bf16
__global__ __launch_bounds__(256) void transpose_x(const float* __restrict__ x,
                                                   u16* __restrict__ xT) {
  __shared__ float tile[64][65];
  const int b = blockIdx.z, p0 = blockIdx.x * 64, c0 = blockIdx.y * 64;
  const int tx = threadIdx.x & 63, ty = threadIdx.x >> 6;
  const float* xb = x + (long)b * (512L * 4096);
  #pragma unroll
  for (int i = ty; i < 64; i += 4)
    tile[i][tx] = xb[(long)(c0 + i) * 4096 + p0 + tx];
  __syncthreads();
  u16* xTb = xT + (long)b * (4096L * 512);
  #pragma unroll
  for (int i = ty; i < 64; i += 4)
    xTb[(long)(p0 + i) * 512 + c0 + tx] = f2bf(tile[tx][i]);
}

// ------------------------------------------------- transpose v -> vT bf16
__global__ __launch_bounds__(256) void transpose_v(const u16* __restrict__ kv,
                                                   u16* __restrict__ vT) {
  __shared__ u16 tile[64][65];
  const int b = blockIdx.z, e0 = blockIdx.x * 64, n0 = blockIdx.y * 64;
  const int tx = threadIdx.x & 63, ty = threadIdx.x >> 6;
  #pragma unroll
  for (int i = ty; i < 64; i += 4)
    tile[i][tx] = kv[(long)(b * 256 + n0 + i) * 1024 + 512 + e0 + tx];
  __syncthreads();
  #pragma unroll
  for (int i = ty; i < 64; i += 4)
    vT[(long)b * (512L * 256) + (long)(e0 + i) * 256 + n0 + tx] = tile[tx][i];
}

// ---------------------------------------------------------------- NT GEMM
// (kv-proj only now) 128x128 tile, BK=32, dbuf global_load_lds, swizzled LDS.
template <int EPI>
__global__ __launch_bounds__(256) void gemm_nt(
    const u16* __restrict__ A, const u16* __restrict__ B, void* __restrict__ Cv,
    int M, int N, int K, long aStrideZ, long bStrideZ, long cStrideZ,
    const float* __restrict__ bias, const float* __restrict__ resid) {
  __shared__ u16 ldsA[2][128 * 32];
  __shared__ u16 ldsB[2][128 * 32];
  const int t = threadIdx.x, wv = t >> 6, ln = t & 63;
  const int m0 = blockIdx.x * 128, n0 = blockIdx.y * 128, z = blockIdx.z;
  const u16* Az = A + (long)z * aStrideZ;
  const u16* Bz = B + (long)z * bStrideZ;
  const int wr = wv >> 1, wc = wv & 1, fr = ln & 15, fq = ln >> 4;

  const u16* aSrc[2];
  const u16* bSrc[2];
  int lbase[2];
  #pragma unroll
  for (int i = 0; i < 2; i++) {
    int c = wv * 64 + ln + i * 256;
    int row = c >> 2, slot = (c & 3) ^ ((c >> 3) & 3);
    aSrc[i] = Az + (long)(m0 + row) * K + slot * 8;
    bSrc[i] = Bz + (long)(n0 + row) * K + slot * 8;
    lbase[i] = (wv * 64 + i * 256) * 8;
  }

  f32x4 acc[4][4] = {};
  const int nk = K >> 5;
  int cur = 0;

  #pragma unroll
  for (int i = 0; i < 2; i++) {
    async16(&ldsA[0][lbase[i]], aSrc[i]);
    async16(&ldsB[0][lbase[i]], bSrc[i]);
  }

  const int swzg = (fr >> 1) & 3;
  for (int kt = 0; kt < nk; ++kt) {
    __syncthreads();
    if (kt + 1 < nk) {
      const int ko = (kt + 1) * 32;
      #pragma unroll
      for (int i = 0; i < 2; i++) {
        async16(&ldsA[cur ^ 1][lbase[i]], aSrc[i] + ko);
        async16(&ldsB[cur ^ 1][lbase[i]], bSrc[i] + ko);
      }
    }
    const char* Ab = (const char*)ldsA[cur];
    const char* Bb = (const char*)ldsB[cur];
    bf16x8 a[4], b[4];
    #pragma unroll
    for (int mf = 0; mf < 4; ++mf)
      a[mf] = *(const bf16x8*)(Ab + (wr * 64 + mf * 16 + fr) * 64 + ((fq ^ swzg) * 16));
    #pragma unroll
    for (int nf = 0; nf < 4; ++nf)
      b[nf] = *(const bf16x8*)(Bb + (wc * 64 + nf * 16 + fr) * 64 + ((fq ^ swzg) * 16));
    #pragma unroll
    for (int mf = 0; mf < 4; ++mf)
      #pragma unroll
      for (int nf = 0; nf < 4; ++nf)
        acc[mf][nf] = mfma16(a[mf], b[nf], acc[mf][nf]);
    cur ^= 1;
  }

  u16* Cb = (u16*)Cv + (long)z * cStrideZ;
  #pragma unroll
  for (int mf = 0; mf < 4; ++mf)
    #pragma unroll
    for (int r = 0; r < 4; ++r) {
      int grow = m0 + wr * 64 + mf * 16 + fq * 4 + r;
      #pragma unroll
      for (int nf = 0; nf < 4; ++nf) {
        int gcol = n0 + wc * 64 + nf * 16 + fr;
        Cb[(long)grow * N + gcol] = f2bf(acc[mf][nf][r]);
      }
    }
}

// ---------------------------------------------------------------- panel GEMM
// For the two big thin GEMMs (long side 4096, other side 512, K=512, weight
// 512x512 L2-resident).  Block = 64-row panel of the long side, staged in LDS
// ONCE at full K (64 KB, swizzled); weight frags stream from L2; fully
// unrolled 16-step K-loop with ZERO barriers after staging.  8 waves, each
// owns 64 weight rows x the 64-row panel: acc[4][4].
// EPI 0 (q-proj):  C[p][e] bf16  = mfma(panel, weight)
// EPI 1 (out-proj): C[c][p] fp32 = mfma(weight, panel) + bias[c] + resid
template <int EPI>
__global__ __launch_bounds__(512, 4) void gemm_panel(
    const u16* __restrict__ P, const u16* __restrict__ W, void* __restrict__ Cv,
    const float* __restrict__ bias, const float* __restrict__ resid) {
  __shared__ u16 plds[64 * 512];  // [p][k] 1KB rows, byte ^= ((p&15)<<4)
  const int t = threadIdx.x, w = t >> 6, ln = t & 63;
  const int fr = ln & 15, fq = ln >> 4;
  const int p0 = blockIdx.x * 64, z = blockIdx.y;
  const u16* Pz = P + (long)z * (4096L * 512) + (long)p0 * 512;

  // stage panel: 4096 chunks of 16B, inverse-swizzled source cols
  #pragma unroll
  for (int i = 0; i < 8; ++i) {
    int cbase = i * 512 + w * 64;      // wave-uniform
    int chunk = cbase + ln;
    int p = chunk >> 6, slot = chunk & 63;
    async16(&plds[cbase * 8], Pz + (long)p * 512 + ((slot ^ (p & 15)) << 3));
  }
  __syncthreads();

  const char* praw = (const char*)plds;
  f32x4 acc[4][4] = {};  // [wf][pf]
  const u16* Wb = W + (long)(w * 64 + fr) * 512;  // this lane's weight rows

  #pragma unroll
  for (int kt = 0; kt < 16; ++kt) {
    bf16x8 wfrag[4], pfrag[4];
    #pragma unroll
    for (int wf = 0; wf < 4; ++wf)
      wfrag[wf] = *(const bf16x8*)&Wb[(long)wf * 16 * 512 + kt * 32 + fq * 8];
    #pragma unroll
    for (int pf = 0; pf < 4; ++pf) {
      int p = pf * 16 + fr;
      pfrag[pf] = *(const bf16x8*)(praw + p * 1024 +
                                   ((kt * 64 + fq * 16) ^ ((p & 15) << 4)));
    }
    #pragma unroll
    for (int wf = 0; wf < 4; ++wf)
      #pragma unroll
      for (int pf = 0; pf < 4; ++pf)
        acc[wf][pf] = (EPI == 0) ? mfma16(pfrag[pf], wfrag[wf], acc[wf][pf])
                                 : mfma16(wfrag[wf], pfrag[pf], acc[wf][pf]);
  }

  if (EPI == 0) {
    // D row = p (fq*4+r), col = e (fr)
    u16* Cb = (u16*)Cv + (long)z * (4096L * 512);
    #pragma unroll
    for (int pf = 0; pf < 4; ++pf)
      #pragma unroll
      for (int r = 0; r < 4; ++r) {
        int p = p0 + pf * 16 + fq * 4 + r;
        #pragma unroll
        for (int wf = 0; wf < 4; ++wf) {
          int e = w * 64 + wf * 16 + fr;
          Cb[(long)p * 512 + e] = f2bf(acc[wf][pf][r]);
        }
      }
  } else {
    // D row = c (fq*4+r), col = p (fr)
    float* Cf = (float*)Cv + (long)z * (512L * 4096);
    const float* Rz = resid + (long)z * (512L * 4096);
    #pragma unroll
    for (int wf = 0; wf < 4; ++wf)
      #pragma unroll
      for (int r = 0; r < 4; ++r) {
        int c = w * 64 + wf * 16 + fq * 4 + r;
        float bv = bias[c];
        #pragma unroll
        for (int pf = 0; pf < 4; ++pf) {
          int p = p0 + pf * 16 + fr;
          long idx = (long)c * 4096 + p;
          Cf[idx] = acc[wf][pf][r] + bv + Rz[idx];
        }
      }
  }
}

// ---------------------------------------------------------------- attention
// (unchanged from round 3)
__global__ __launch_bounds__(512) void attn_kernel(
    const u16* __restrict__ q, const u16* __restrict__ kv,
    const u16* __restrict__ vT, u16* __restrict__ ao) {
  __shared__ u16 klds[256 * 64];
  __shared__ u16 vlds[64 * 256];
  __shared__ u16 plds[128 * 256];
  const int t = threadIdx.x, w = t >> 6, ln = t & 63;
  const int fr = ln & 15, fq = ln >> 4;
  const int p0 = blockIdx.x * 1024, h = blockIdx.y, b = blockIdx.z;

  const u16* kb = kv + (long)b * 256 * 1024 + h * 64;
  const u16* vb = vT + (long)b * (512L * 256) + (long)h * 64 * 256;

  #pragma unroll
  for (int i = 0; i < 4; ++i) {
    int cbase = i * 512 + w * 64;
    int chunk = cbase + ln;
    int row = chunk >> 3, slot = chunk & 7;
    async16(&klds[cbase * 8], kb + (long)row * 1024 + ((slot ^ (row & 7)) << 3));
  }
  #pragma unroll
  for (int i = 0; i < 4; ++i) {
    int cbase = i * 512 + w * 64;
    int chunk = cbase + ln;
    int row = chunk >> 5, slot = chunk & 31;
    async16(&vlds[cbase * 8], vb + (long)row * 256 + ((slot ^ (row & 7)) << 3));
  }
  __syncthreads();

  const char* kraw = (const char*)klds;
  const char* vraw = (const char*)vlds;
  char* praw = (char*)plds;
  const int prowL = w * 16 + fr;
  const int swz = (fr & 7) << 4;

  const u16* qbase = q + ((long)b * 4096 + p0 + w * 16 + fr) * 512 + h * 64;
  bf16x8 qf0 = *(const bf16x8*)&qbase[fq * 8];
  bf16x8 qf1 = *(const bf16x8*)&qbase[32 + fq * 8];

  for (int it = 0; it < 8; ++it) {
    f32x4 s[16] = {};
    #pragma unroll
    for (int nb = 0; nb < 16; ++nb) {
      int n = nb * 16 + fr;
      bf16x8 kf0 = *(const bf16x8*)(kraw + n * 128 + ((fq * 16) ^ swz));
      bf16x8 kf1 = *(const bf16x8*)(kraw + n * 128 + ((64 + fq * 16) ^ swz));
      s[nb] = mfma16(kf0, qf0, s[nb]);
      s[nb] = mfma16(kf1, qf1, s[nb]);
    }

    const u16* qn = qbase + (long)(((it + 1) & 7) * 128) * 512;
    bf16x8 qn0 = *(const bf16x8*)&qn[fq * 8];
    bf16x8 qn1 = *(const bf16x8*)&qn[32 + fq * 8];

    f32x4 mx = s[0];
    #pragma unroll
    for (int nb = 1; nb < 16; ++nb) {
      mx[0] = fmaxf(mx[0], s[nb][0]); mx[1] = fmaxf(mx[1], s[nb][1]);
      mx[2] = fmaxf(mx[2], s[nb][2]); mx[3] = fmaxf(mx[3], s[nb][3]);
    }
    float m = fmaxf(fmaxf(mx[0], mx[1]), fmaxf(mx[2], mx[3]));
    m = fmaxf(m, __shfl_xor(m, 16));
    m = fmaxf(m, __shfl_xor(m, 32));
    f32x4 sm = {0.f, 0.f, 0.f, 0.f};
    #pragma unroll
    for (int nb = 0; nb < 16; ++nb) {
      #pragma unroll
      for (int r = 0; r < 4; ++r)
        s[nb][r] = __builtin_amdgcn_exp2f(s[nb][r] - m);
      sm += s[nb];
    }
    float sum = (sm[0] + sm[1]) + (sm[2] + sm[3]);
    sum += __shfl_xor(sum, 16);
    sum += __shfl_xor(sum, 32);
    float inv = 1.0f / sum;

    #pragma unroll
    for (int nb = 0; nb < 16; ++nb) {
      bf16x4 pk;
      #pragma unroll
      for (int r = 0; r < 4; ++r) pk[r] = (__bf16)s[nb][r];
      *(bf16x4*)(praw + prowL * 512 + ((nb * 32 + fq * 8) ^ swz)) = pk;
    }
    asm volatile("s_waitcnt lgkmcnt(0)" ::: "memory");
    __builtin_amdgcn_sched_barrier(0);

    f32x4 o[4] = {};
    #pragma unroll
    for (int kk2 = 0; kk2 < 8; ++kk2) {
      bf16x8 pf = *(const bf16x8*)(praw + prowL * 512 + ((kk2 * 64 + fq * 16) ^ swz));
      #pragma unroll
      for (int nfd = 0; nfd < 4; ++nfd) {
        bf16x8 vf = *(const bf16x8*)(vraw + (nfd * 16 + fr) * 512 +
                                     ((kk2 * 64 + fq * 16) ^ swz));
        o[nfd] = mfma16(vf, pf, o[nfd]);
      }
    }

    u16* aob = ao + ((long)b * 4096 + p0 + it * 128 + w * 16 + fr) * 512 + h * 64;
    #pragma unroll
    for (int nfd = 0; nfd < 4; ++nfd) {
      bf16x4 ov;
      #pragma unroll
      for (int r = 0; r < 4; ++r) ov[r] = (__bf16)(o[nfd][r] * inv);
      *(bf16x4*)(aob + nfd * 16 + fq * 4) = ov;
    }
    qf0 = qn0;
    qf1 = qn1;
  }
}

// ---------------------------------------------------------------- launch
extern "C" void kernel_launch(void* const* d_in, const int* in_sizes, int n_in,
                              void* d_out, int out_size, void* d_ws, size_t ws_size,
                              hipStream_t stream) {
  const float* x    = (const float*)d_in[0];
  const float* ctx  = (const float*)d_in[1];
  const float* Wq   = (const float*)d_in[2];
  const float* Wkv  = (const float*)d_in[3];
  const float* Wout = (const float*)d_in[4];
  const float* bout = (const float*)d_in[5];
  float* out = (float*)d_out;
  char* ws = (char*)d_ws;

  u16* xT     = (u16*)(ws);              // 33,554,432 B (reused as ao)
  u16* q      = (u16*)(ws + 33554432);   // 33,554,432 B
  u16* kv     = (u16*)(ws + 67108864);   //  4,194,304 B
  u16* vT     = (u16*)(ws + 71303168);   //  2,097,152 B
  u16* Wq_b   = (u16*)(ws + 73400320);   //    524,288 B
  u16* Wkv_b  = (u16*)(ws + 73924608);   //  1,572,864 B
  u16* Wout_b = (u16*)(ws + 75497472);   //    524,288 B
  u16* ctx_b  = (u16*)(ws + 76021760);   //  3,145,728 B
  u16* ao     = xT;

  prep_cast<<<dim3(1024), dim3(256), 0, stream>>>(Wq, Wkv, Wout, ctx,
                                                  Wq_b, Wkv_b, Wout_b, ctx_b);
  transpose_x<<<dim3(64, 8, 8), dim3(256), 0, stream>>>(x, xT);
  // q[b][p][e] = sum_c xT[b][p][c] * (Wq*scale)[e][c]
  gemm_panel<0><<<dim3(64, 8), dim3(512), 0, stream>>>(
      xT, Wq_b, (void*)q, nullptr, nullptr);
  // kv[bn][e2] = sum_c ctx[bn][c] * Wkv[e2][c]
  gemm_nt<0><<<dim3(16, 8, 1), dim3(256), 0, stream>>>(
      ctx_b, Wkv_b, (void*)kv, 2048, 1024, 768, 0L, 0L, 0L, nullptr, nullptr);
  transpose_v<<<dim3(8, 4, 8), dim3(256), 0, stream>>>(kv, vT);
  attn_kernel<<<dim3(4, 8, 8), dim3(512), 0, stream>>>(q, kv, vT, ao);
  // out[b][c][p] = sum_e Wout[c][e] * ao[b][p][e] + bout[c] + x[b][c][p]
  gemm_panel<1><<<dim3(64, 8), dim3(512), 0, stream>>>(
      ao, Wout_b, (void*)out, bout, x);
}

// Round 5
// 145.318 us; speedup vs baseline: 1.2009x; 1.2009x over previous
//
#include <hip/hip_runtime.h>

typedef unsigned short u16;
typedef __bf16 bf16x8 __attribute__((ext_vector_type(8)));
typedef __bf16 bf16x4 __attribute__((ext_vector_type(4)));
typedef float f32x4 __attribute__((ext_vector_type(4)));

__device__ __forceinline__ u16 f2bf(float f) {
  __bf16 h = (__bf16)f;
  return *(u16*)&h;
}

__device__ __forceinline__ f32x4 mfma16(bf16x8 a, bf16x8 b, f32x4 c) {
  return __builtin_amdgcn_mfma_f32_16x16x32_bf16(a, b, c, 0, 0, 0);
}

__device__ __forceinline__ void async16(void* lds, const void* g) {
  __builtin_amdgcn_global_load_lds(
      (const __attribute__((address_space(1))) unsigned int*)g,
      (__attribute__((address_space(3))) unsigned int*)lds, 16, 0, 0);
}

// fold softmax scale AND log2(e) into Wq so softmax uses raw v_exp_f32 (exp2)
#define QSCALE 0.18033688011112042f  // 0.125 * log2(e)

// ---------------------------------------------------------------- prep: casts
__global__ __launch_bounds__(256) void prep_cast(
    const float* __restrict__ Wq, const float* __restrict__ Wkv,
    const float* __restrict__ Wout, const float* __restrict__ ctx,
    u16* __restrict__ Wq_b, u16* __restrict__ Wkv_b,
    u16* __restrict__ Wout_b, u16* __restrict__ ctx_b) {
  const long NWQ = 512L * 512, NWKV = 1024L * 768, NWOUT = 512L * 512, NCTX = 2048L * 768;
  const long total = NWQ + NWKV + NWOUT + NCTX;
  long stride = (long)gridDim.x * 256;
  for (long i = (long)blockIdx.x * 256 + threadIdx.x; i < total; i += stride) {
    long j = i;
    if (j < NWQ) { Wq_b[j] = f2bf(Wq[j] * QSCALE); continue; }
    j -= NWQ;
    if (j < NWKV) { Wkv_b[j] = f2bf(Wkv[j]); continue; }
    j -= NWKV;
    if (j < NWOUT) { Wout_b[j] = f2bf(Wout[j]); continue; }
    j -= NWOUT;
    ctx_b[j] = f2bf(ctx[j]);
  }
}

// ------------------------------------------------- transpose x -> xT bf16
__global__ __launch_bounds__(256) void transpose_x(const float* __restrict__ x,
                                                   u16* __restrict__ xT) {
  __shared__ float tile[64][65];
  const int b = blockIdx.z, p0 = blockIdx.x * 64, c0 = blockIdx.y * 64;
  const int tx = threadIdx.x & 63, ty = threadIdx.x >> 6;
  const float* xb = x + (long)b * (512L * 4096);
  #pragma unroll
  for (int i = ty; i < 64; i += 4)
    tile[i][tx] = xb[(long)(c0 + i) * 4096 + p0 + tx];
  __syncthreads();
  u16* xTb = xT + (long)b * (4096L * 512);
  #pragma unroll
  for (int i = ty; i < 64; i += 4)
    xTb[(long)(p0 + i) * 512 + c0 + tx] = f2bf(tile[tx][i]);
}

// ------------------------------------------------- transpose v -> vT bf16
__global__ __launch_bounds__(256) void transpose_v(const u16* __restrict__ kv,
                                                   u16* __restrict__ vT) {
  __shared__ u16 tile[64][65];
  const int b = blockIdx.z, e0 = blockIdx.x * 64, n0 = blockIdx.y * 64;
  const int tx = threadIdx.x & 63, ty = threadIdx.x >> 6;
  #pragma unroll
  for (int i = ty; i < 64; i += 4)
    tile[i][tx] = kv[(long)(b * 256 + n0 + i) * 1024 + 512 + e0 + tx];
  __syncthreads();
  #pragma unroll
  for (int i = ty; i < 64; i += 4)
    vT[(long)b * (512L * 256) + (long)(e0 + i) * 256 + n0 + tx] = tile[tx][i];
}

// ---------------------------------------------------------------- NT GEMM
// C[M][N] = A[M][K] . B[N][K]^T.  m97-faithful: 128x128 tile, BK=64,
// double-buffered global_load_lds width 16, 32 MFMA per barrier pair.
// LDS rows 128B, swizzle byte ^= ((row&7)<<4) (2-way banks = free),
// applied as inverse-swizzled global source + swizzled ds_read_b128.
// EPI 0: bf16 store.  EPI 1: fp32 + bias[row] + resid.
template <int EPI>
__global__ __launch_bounds__(256) void gemm_nt(
    const u16* __restrict__ A, const u16* __restrict__ B, void* __restrict__ Cv,
    int M, int N, int K, long aStrideZ, long bStrideZ, long cStrideZ,
    const float* __restrict__ bias, const float* __restrict__ resid) {
  __shared__ u16 ldsA[2][128 * 64];   // 16 KB per buffer
  __shared__ u16 ldsB[2][128 * 64];
  const int t = threadIdx.x, wv = t >> 6, ln = t & 63;
  const int m0 = blockIdx.x * 128, n0 = blockIdx.y * 128, z = blockIdx.z;
  const u16* Az = A + (long)z * aStrideZ;
  const u16* Bz = B + (long)z * bStrideZ;
  const int wr = wv >> 1, wc = wv & 1, fr = ln & 15, fq = ln >> 4;

  // staging: 1024 chunks of 16B per array; chunk c -> row c>>3, slot c&7
  const u16* aSrc[4];
  const u16* bSrc[4];
  int lbase[4];
  #pragma unroll
  for (int i = 0; i < 4; i++) {
    int c = i * 256 + wv * 64 + ln;
    int row = c >> 3, slot = (c & 7) ^ (row & 7);   // inverse swizzle
    aSrc[i] = Az + (long)(m0 + row) * K + slot * 8;
    bSrc[i] = Bz + (long)(n0 + row) * K + slot * 8;
    lbase[i] = (i * 256 + wv * 64) * 8;             // u16 elems; HW adds lane*16B
  }

  f32x4 acc[4][4] = {};
  const int nk = K >> 6;
  int cur = 0;

  #pragma unroll
  for (int i = 0; i < 4; i++) {
    async16(&ldsA[0][lbase[i]], aSrc[i]);
    async16(&ldsB[0][lbase[i]], bSrc[i]);
  }

  for (int kt = 0; kt < nk; ++kt) {
    __syncthreads();   // compiler drains vmcnt/lgkmcnt before barrier
    if (kt + 1 < nk) {
      const int ko = (kt + 1) * 64;
      #pragma unroll
      for (int i = 0; i < 4; i++) {
        async16(&ldsA[cur ^ 1][lbase[i]], aSrc[i] + ko);
        async16(&ldsB[cur ^ 1][lbase[i]], bSrc[i] + ko);
      }
    }
    const char* Ab = (const char*)ldsA[cur];
    const char* Bb = (const char*)ldsB[cur];
    bf16x8 a[2][4], b[2][4];
    #pragma unroll
    for (int kk = 0; kk < 2; ++kk) {
      #pragma unroll
      for (int mf = 0; mf < 4; ++mf) {
        int row = wr * 64 + mf * 16 + fr;
        a[kk][mf] = *(const bf16x8*)(Ab + row * 128 +
                                     ((kk * 64 + fq * 16) ^ ((row & 7) << 4)));
      }
      #pragma unroll
      for (int nf = 0; nf < 4; ++nf) {
        int row = wc * 64 + nf * 16 + fr;
        b[kk][nf] = *(const bf16x8*)(Bb + row * 128 +
                                     ((kk * 64 + fq * 16) ^ ((row & 7) << 4)));
      }
    }
    #pragma unroll
    for (int kk = 0; kk < 2; ++kk)
      #pragma unroll
      for (int mf = 0; mf < 4; ++mf)
        #pragma unroll
        for (int nf = 0; nf < 4; ++nf)
          acc[mf][nf] = mfma16(a[kk][mf], b[kk][nf], acc[mf][nf]);
    cur ^= 1;
  }

  if (EPI == 0) {
    u16* Cb = (u16*)Cv + (long)z * cStrideZ;
    #pragma unroll
    for (int mf = 0; mf < 4; ++mf)
      #pragma unroll
      for (int r = 0; r < 4; ++r) {
        int grow = m0 + wr * 64 + mf * 16 + fq * 4 + r;
        #pragma unroll
        for (int nf = 0; nf < 4; ++nf) {
          int gcol = n0 + wc * 64 + nf * 16 + fr;
          Cb[(long)grow * N + gcol] = f2bf(acc[mf][nf][r]);
        }
      }
  } else {
    float* Cf = (float*)Cv + (long)z * cStrideZ;
    const float* Rz = resid + (long)z * cStrideZ;
    #pragma unroll
    for (int mf = 0; mf < 4; ++mf)
      #pragma unroll
      for (int r = 0; r < 4; ++r) {
        int grow = m0 + wr * 64 + mf * 16 + fq * 4 + r;
        float bv = bias[grow];
        #pragma unroll
        for (int nf = 0; nf < 4; ++nf) {
          int gcol = n0 + wc * 64 + nf * 16 + fr;
          long idx = (long)grow * N + gcol;
          Cf[idx] = acc[mf][nf][r] + bv + Rz[idx];
        }
      }
  }
}

// ---------------------------------------------------------------- attention
// (round-3 structure, unchanged)
__global__ __launch_bounds__(512) void attn_kernel(
    const u16* __restrict__ q, const u16* __restrict__ kv,
    const u16* __restrict__ vT, u16* __restrict__ ao) {
  __shared__ u16 klds[256 * 64];
  __shared__ u16 vlds[64 * 256];
  __shared__ u16 plds[128 * 256];
  const int t = threadIdx.x, w = t >> 6, ln = t & 63;
  const int fr = ln & 15, fq = ln >> 4;
  const int p0 = blockIdx.x * 1024, h = blockIdx.y, b = blockIdx.z;

  const u16* kb = kv + (long)b * 256 * 1024 + h * 64;
  const u16* vb = vT + (long)b * (512L * 256) + (long)h * 64 * 256;

  #pragma unroll
  for (int i = 0; i < 4; ++i) {
    int cbase = i * 512 + w * 64;
    int chunk = cbase + ln;
    int row = chunk >> 3, slot = chunk & 7;
    async16(&klds[cbase * 8], kb + (long)row * 1024 + ((slot ^ (row & 7)) << 3));
  }
  #pragma unroll
  for (int i = 0; i < 4; ++i) {
    int cbase = i * 512 + w * 64;
    int chunk = cbase + ln;
    int row = chunk >> 5, slot = chunk & 31;
    async16(&vlds[cbase * 8], vb + (long)row * 256 + ((slot ^ (row & 7)) << 3));
  }
  __syncthreads();

  const char* kraw = (const char*)klds;
  const char* vraw = (const char*)vlds;
  char* praw = (char*)plds;
  const int prowL = w * 16 + fr;
  const int swz = (fr & 7) << 4;

  const u16* qbase = q + ((long)b * 4096 + p0 + w * 16 + fr) * 512 + h * 64;
  bf16x8 qf0 = *(const bf16x8*)&qbase[fq * 8];
  bf16x8 qf1 = *(const bf16x8*)&qbase[32 + fq * 8];

  for (int it = 0; it < 8; ++it) {
    f32x4 s[16] = {};
    #pragma unroll
    for (int nb = 0; nb < 16; ++nb) {
      int n = nb * 16 + fr;
      bf16x8 kf0 = *(const bf16x8*)(kraw + n * 128 + ((fq * 16) ^ swz));
      bf16x8 kf1 = *(const bf16x8*)(kraw + n * 128 + ((64 + fq * 16) ^ swz));
      s[nb] = mfma16(kf0, qf0, s[nb]);
      s[nb] = mfma16(kf1, qf1, s[nb]);
    }

    const u16* qn = qbase + (long)(((it + 1) & 7) * 128) * 512;
    bf16x8 qn0 = *(const bf16x8*)&qn[fq * 8];
    bf16x8 qn1 = *(const bf16x8*)&qn[32 + fq * 8];

    f32x4 mx = s[0];
    #pragma unroll
    for (int nb = 1; nb < 16; ++nb) {
      mx[0] = fmaxf(mx[0], s[nb][0]); mx[1] = fmaxf(mx[1], s[nb][1]);
      mx[2] = fmaxf(mx[2], s[nb][2]); mx[3] = fmaxf(mx[3], s[nb][3]);
    }
    float m = fmaxf(fmaxf(mx[0], mx[1]), fmaxf(mx[2], mx[3]));
    m = fmaxf(m, __shfl_xor(m, 16));
    m = fmaxf(m, __shfl_xor(m, 32));
    f32x4 sm = {0.f, 0.f, 0.f, 0.f};
    #pragma unroll
    for (int nb = 0; nb < 16; ++nb) {
      #pragma unroll
      for (int r = 0; r < 4; ++r)
        s[nb][r] = __builtin_amdgcn_exp2f(s[nb][r] - m);
      sm += s[nb];
    }
    float sum = (sm[0] + sm[1]) + (sm[2] + sm[3]);
    sum += __shfl_xor(sum, 16);
    sum += __shfl_xor(sum, 32);
    float inv = 1.0f / sum;

    #pragma unroll
    for (int nb = 0; nb < 16; ++nb) {
      bf16x4 pk;
      #pragma unroll
      for (int r = 0; r < 4; ++r) pk[r] = (__bf16)s[nb][r];
      *(bf16x4*)(praw + prowL * 512 + ((nb * 32 + fq * 8) ^ swz)) = pk;
    }
    asm volatile("s_waitcnt lgkmcnt(0)" ::: "memory");
    __builtin_amdgcn_sched_barrier(0);

    f32x4 o[4] = {};
    #pragma unroll
    for (int kk2 = 0; kk2 < 8; ++kk2) {
      bf16x8 pf = *(const bf16x8*)(praw + prowL * 512 + ((kk2 * 64 + fq * 16) ^ swz));
      #pragma unroll
      for (int nfd = 0; nfd < 4; ++nfd) {
        bf16x8 vf = *(const bf16x8*)(vraw + (nfd * 16 + fr) * 512 +
                                     ((kk2 * 64 + fq * 16) ^ swz));
        o[nfd] = mfma16(vf, pf, o[nfd]);
      }
    }

    u16* aob = ao + ((long)b * 4096 + p0 + it * 128 + w * 16 + fr) * 512 + h * 64;
    #pragma unroll
    for (int nfd = 0; nfd < 4; ++nfd) {
      bf16x4 ov;
      #pragma unroll
      for (int r = 0; r < 4; ++r) ov[r] = (__bf16)(o[nfd][r] * inv);
      *(bf16x4*)(aob + nfd * 16 + fq * 4) = ov;
    }
    qf0 = qn0;
    qf1 = qn1;
  }
}

// ---------------------------------------------------------------- launch
extern "C" void kernel_launch(void* const* d_in, const int* in_sizes, int n_in,
                              void* d_out, int out_size, void* d_ws, size_t ws_size,
                              hipStream_t stream) {
  const float* x    = (const float*)d_in[0];
  const float* ctx  = (const float*)d_in[1];
  const float* Wq   = (const float*)d_in[2];
  const float* Wkv  = (const float*)d_in[3];
  const float* Wout = (const float*)d_in[4];
  const float* bout = (const float*)d_in[5];
  float* out = (float*)d_out;
  char* ws = (char*)d_ws;

  u16* xT     = (u16*)(ws);              // 33,554,432 B (reused as ao)
  u16* q      = (u16*)(ws + 33554432);   // 33,554,432 B
  u16* kv     = (u16*)(ws + 67108864);   //  4,194,304 B
  u16* vT     = (u16*)(ws + 71303168);   //  2,097,152 B
  u16* Wq_b   = (u16*)(ws + 73400320);   //    524,288 B
  u16* Wkv_b  = (u16*)(ws + 73924608);   //  1,572,864 B
  u16* Wout_b = (u16*)(ws + 75497472);   //    524,288 B
  u16* ctx_b  = (u16*)(ws + 76021760);   //  3,145,728 B
  u16* ao     = xT;

  prep_cast<<<dim3(1024), dim3(256), 0, stream>>>(Wq, Wkv, Wout, ctx,
                                                  Wq_b, Wkv_b, Wout_b, ctx_b);
  transpose_x<<<dim3(64, 8, 8), dim3(256), 0, stream>>>(x, xT);
  // q[b][p][e] = sum_c xT[b][p][c] * (Wq*scale)[e][c]
  gemm_nt<0><<<dim3(32, 4, 8), dim3(256), 0, stream>>>(
      xT, Wq_b, (void*)q, 4096, 512, 512, 4096L * 512, 0L, 4096L * 512,
      nullptr, nullptr);
  // kv[bn][e2] = sum_c ctx[bn][c] * Wkv[e2][c]
  gemm_nt<0><<<dim3(16, 8, 1), dim3(256), 0, stream>>>(
      ctx_b, Wkv_b, (void*)kv, 2048, 1024, 768, 0L, 0L, 0L, nullptr, nullptr);
  transpose_v<<<dim3(8, 4, 8), dim3(256), 0, stream>>>(kv, vT);
  attn_kernel<<<dim3(4, 8, 8), dim3(512), 0, stream>>>(q, kv, vT, ao);
  // out[b][c][p] = sum_e Wout[c][e] * ao[b][p][e] + bout[c] + x[b][c][p]
  gemm_nt<1><<<dim3(4, 32, 8), dim3(256), 0, stream>>>(
      Wout_b, ao, (void*)out, 512, 4096, 512, 0L, 4096L * 512, 512L * 4096,
      bout, x);
}

// Round 6
// 143.808 us; speedup vs baseline: 1.2135x; 1.0105x over previous
//
#include <hip/hip_runtime.h>

typedef unsigned short u16;
typedef __bf16 bf16x8 __attribute__((ext_vector_type(8)));
typedef __bf16 bf16x4 __attribute__((ext_vector_type(4)));
typedef float f32x4 __attribute__((ext_vector_type(4)));

__device__ __forceinline__ u16 f2bf(float f) {
  __bf16 h = (__bf16)f;
  return *(u16*)&h;
}

__device__ __forceinline__ f32x4 mfma16(bf16x8 a, bf16x8 b, f32x4 c) {
  return __builtin_amdgcn_mfma_f32_16x16x32_bf16(a, b, c, 0, 0, 0);
}

__device__ __forceinline__ void async16(void* lds, const void* g) {
  __builtin_amdgcn_global_load_lds(
      (const __attribute__((address_space(1))) unsigned int*)g,
      (__attribute__((address_space(3))) unsigned int*)lds, 16, 0, 0);
}

// fold softmax scale AND log2(e) into Wq so softmax uses raw v_exp_f32 (exp2)
#define QSCALE 0.18033688011112042f  // 0.125 * log2(e)

// ---------------------------------------------------------------- prep: casts
__global__ __launch_bounds__(256) void prep_cast(
    const float* __restrict__ Wq, const float* __restrict__ Wkv,
    const float* __restrict__ Wout, const float* __restrict__ ctx,
    u16* __restrict__ Wq_b, u16* __restrict__ Wkv_b,
    u16* __restrict__ Wout_b, u16* __restrict__ ctx_b) {
  const long NWQ = 512L * 512, NWKV = 1024L * 768, NWOUT = 512L * 512, NCTX = 2048L * 768;
  const long total = NWQ + NWKV + NWOUT + NCTX;
  long stride = (long)gridDim.x * 256;
  for (long i = (long)blockIdx.x * 256 + threadIdx.x; i < total; i += stride) {
    long j = i;
    if (j < NWQ) { Wq_b[j] = f2bf(Wq[j] * QSCALE); continue; }
    j -= NWQ;
    if (j < NWKV) { Wkv_b[j] = f2bf(Wkv[j]); continue; }
    j -= NWKV;
    if (j < NWOUT) { Wout_b[j] = f2bf(Wout[j]); continue; }
    j -= NWOUT;
    ctx_b[j] = f2bf(ctx[j]);
  }
}

// ------------------------------------------------- transpose x -> xT bf16
__global__ __launch_bounds__(256) void transpose_x(const float* __restrict__ x,
                                                   u16* __restrict__ xT) {
  __shared__ float tile[64][65];
  const int b = blockIdx.z, p0 = blockIdx.x * 64, c0 = blockIdx.y * 64;
  const int tx = threadIdx.x & 63, ty = threadIdx.x >> 6;
  const float* xb = x + (long)b * (512L * 4096);
  #pragma unroll
  for (int i = ty; i < 64; i += 4)
    tile[i][tx] = xb[(long)(c0 + i) * 4096 + p0 + tx];
  __syncthreads();
  u16* xTb = xT + (long)b * (4096L * 512);
  #pragma unroll
  for (int i = ty; i < 64; i += 4)
    xTb[(long)(p0 + i) * 512 + c0 + tx] = f2bf(tile[tx][i]);
}

// ------------------------------------------------- transpose v -> vT bf16
__global__ __launch_bounds__(256) void transpose_v(const u16* __restrict__ kv,
                                                   u16* __restrict__ vT) {
  __shared__ u16 tile[64][65];
  const int b = blockIdx.z, e0 = blockIdx.x * 64, n0 = blockIdx.y * 64;
  const int tx = threadIdx.x & 63, ty = threadIdx.x >> 6;
  #pragma unroll
  for (int i = ty; i < 64; i += 4)
    tile[i][tx] = kv[(long)(b * 256 + n0 + i) * 1024 + 512 + e0 + tx];
  __syncthreads();
  #pragma unroll
  for (int i = ty; i < 64; i += 4)
    vT[(long)b * (512L * 256) + (long)(e0 + i) * 256 + n0 + tx] = tile[tx][i];
}

// ---------------------------------------------------------------- NT GEMM
// C[M][N] = A[M][K] . B[N][K]^T.  128x128 tile, BK=64, dbuf global_load_lds
// width 16, 32 MFMA per barrier pair, swizzled LDS (2-way banks = free).
// EPI 0: bf16 store.
// EPI 1: fp32 + bias[row] + resid; resid/bias PRE-LOADED into registers at
//        kernel start so the 134 MB epilogue stream overlaps the K-loop.
template <int EPI>
__global__ __launch_bounds__(256) void gemm_nt(
    const u16* __restrict__ A, const u16* __restrict__ B, void* __restrict__ Cv,
    int M, int N, int K, long aStrideZ, long bStrideZ, long cStrideZ,
    const float* __restrict__ bias, const float* __restrict__ resid) {
  __shared__ u16 ldsA[2][128 * 64];   // 16 KB per buffer
  __shared__ u16 ldsB[2][128 * 64];
  const int t = threadIdx.x, wv = t >> 6, ln = t & 63;
  const int m0 = blockIdx.x * 128, n0 = blockIdx.y * 128, z = blockIdx.z;
  const u16* Az = A + (long)z * aStrideZ;
  const u16* Bz = B + (long)z * bStrideZ;
  const int wr = wv >> 1, wc = wv & 1, fr = ln & 15, fq = ln >> 4;

  // ---- EPI 1: prefetch resid + bias into registers (overlaps K-loop traffic)
  float rpre[4][4][4];  // [mf][r][nf] — all indices static after unroll
  float bpre[4][4];
  if (EPI == 1) {
    const float* Rz = resid + (long)z * cStrideZ;
    #pragma unroll
    for (int mf = 0; mf < 4; ++mf)
      #pragma unroll
      for (int r = 0; r < 4; ++r) {
        int grow = m0 + wr * 64 + mf * 16 + fq * 4 + r;
        bpre[mf][r] = bias[grow];
        #pragma unroll
        for (int nf = 0; nf < 4; ++nf) {
          int gcol = n0 + wc * 64 + nf * 16 + fr;
          rpre[mf][r][nf] = Rz[(long)grow * N + gcol];
        }
      }
    __builtin_amdgcn_sched_barrier(0);  // pin issue before staging
  }

  // staging: 1024 chunks of 16B per array; chunk c -> row c>>3, slot c&7
  const u16* aSrc[4];
  const u16* bSrc[4];
  int lbase[4];
  #pragma unroll
  for (int i = 0; i < 4; i++) {
    int c = i * 256 + wv * 64 + ln;
    int row = c >> 3, slot = (c & 7) ^ (row & 7);   // inverse swizzle
    aSrc[i] = Az + (long)(m0 + row) * K + slot * 8;
    bSrc[i] = Bz + (long)(n0 + row) * K + slot * 8;
    lbase[i] = (i * 256 + wv * 64) * 8;             // u16 elems; HW adds lane*16B
  }

  f32x4 acc[4][4] = {};
  const int nk = K >> 6;
  int cur = 0;

  #pragma unroll
  for (int i = 0; i < 4; i++) {
    async16(&ldsA[0][lbase[i]], aSrc[i]);
    async16(&ldsB[0][lbase[i]], bSrc[i]);
  }

  for (int kt = 0; kt < nk; ++kt) {
    __syncthreads();   // compiler drains vmcnt/lgkmcnt before barrier
    if (kt + 1 < nk) {
      const int ko = (kt + 1) * 64;
      #pragma unroll
      for (int i = 0; i < 4; i++) {
        async16(&ldsA[cur ^ 1][lbase[i]], aSrc[i] + ko);
        async16(&ldsB[cur ^ 1][lbase[i]], bSrc[i] + ko);
      }
    }
    const char* Ab = (const char*)ldsA[cur];
    const char* Bb = (const char*)ldsB[cur];
    bf16x8 a[2][4], b[2][4];
    #pragma unroll
    for (int kk = 0; kk < 2; ++kk) {
      #pragma unroll
      for (int mf = 0; mf < 4; ++mf) {
        int row = wr * 64 + mf * 16 + fr;
        a[kk][mf] = *(const bf16x8*)(Ab + row * 128 +
                                     ((kk * 64 + fq * 16) ^ ((row & 7) << 4)));
      }
      #pragma unroll
      for (int nf = 0; nf < 4; ++nf) {
        int row = wc * 64 + nf * 16 + fr;
        b[kk][nf] = *(const bf16x8*)(Bb + row * 128 +
                                     ((kk * 64 + fq * 16) ^ ((row & 7) << 4)));
      }
    }
    #pragma unroll
    for (int kk = 0; kk < 2; ++kk)
      #pragma unroll
      for (int mf = 0; mf < 4; ++mf)
        #pragma unroll
        for (int nf = 0; nf < 4; ++nf)
          acc[mf][nf] = mfma16(a[kk][mf], b[kk][nf], acc[mf][nf]);
    cur ^= 1;
  }

  if (EPI == 0) {
    u16* Cb = (u16*)Cv + (long)z * cStrideZ;
    #pragma unroll
    for (int mf = 0; mf < 4; ++mf)
      #pragma unroll
      for (int r = 0; r < 4; ++r) {
        int grow = m0 + wr * 64 + mf * 16 + fq * 4 + r;
        #pragma unroll
        for (int nf = 0; nf < 4; ++nf) {
          int gcol = n0 + wc * 64 + nf * 16 + fr;
          Cb[(long)grow * N + gcol] = f2bf(acc[mf][nf][r]);
        }
      }
  } else {
    float* Cf = (float*)Cv + (long)z * cStrideZ;
    #pragma unroll
    for (int mf = 0; mf < 4; ++mf)
      #pragma unroll
      for (int r = 0; r < 4; ++r) {
        int grow = m0 + wr * 64 + mf * 16 + fq * 4 + r;
        #pragma unroll
        for (int nf = 0; nf < 4; ++nf) {
          int gcol = n0 + wc * 64 + nf * 16 + fr;
          Cf[(long)grow * N + gcol] = acc[mf][nf][r] + bpre[mf][r] + rpre[mf][r][nf];
        }
      }
  }
}

// ---------------------------------------------------------------- attention
// (round-3 structure + T5 setprio around MFMA clusters)
__global__ __launch_bounds__(512) void attn_kernel(
    const u16* __restrict__ q, const u16* __restrict__ kv,
    const u16* __restrict__ vT, u16* __restrict__ ao) {
  __shared__ u16 klds[256 * 64];
  __shared__ u16 vlds[64 * 256];
  __shared__ u16 plds[128 * 256];
  const int t = threadIdx.x, w = t >> 6, ln = t & 63;
  const int fr = ln & 15, fq = ln >> 4;
  const int p0 = blockIdx.x * 1024, h = blockIdx.y, b = blockIdx.z;

  const u16* kb = kv + (long)b * 256 * 1024 + h * 64;
  const u16* vb = vT + (long)b * (512L * 256) + (long)h * 64 * 256;

  #pragma unroll
  for (int i = 0; i < 4; ++i) {
    int cbase = i * 512 + w * 64;
    int chunk = cbase + ln;
    int row = chunk >> 3, slot = chunk & 7;
    async16(&klds[cbase * 8], kb + (long)row * 1024 + ((slot ^ (row & 7)) << 3));
  }
  #pragma unroll
  for (int i = 0; i < 4; ++i) {
    int cbase = i * 512 + w * 64;
    int chunk = cbase + ln;
    int row = chunk >> 5, slot = chunk & 31;
    async16(&vlds[cbase * 8], vb + (long)row * 256 + ((slot ^ (row & 7)) << 3));
  }
  __syncthreads();

  const char* kraw = (const char*)klds;
  const char* vraw = (const char*)vlds;
  char* praw = (char*)plds;
  const int prowL = w * 16 + fr;
  const int swz = (fr & 7) << 4;

  const u16* qbase = q + ((long)b * 4096 + p0 + w * 16 + fr) * 512 + h * 64;
  bf16x8 qf0 = *(const bf16x8*)&qbase[fq * 8];
  bf16x8 qf1 = *(const bf16x8*)&qbase[32 + fq * 8];

  for (int it = 0; it < 8; ++it) {
    f32x4 s[16] = {};
    __builtin_amdgcn_s_setprio(1);
    #pragma unroll
    for (int nb = 0; nb < 16; ++nb) {
      int n = nb * 16 + fr;
      bf16x8 kf0 = *(const bf16x8*)(kraw + n * 128 + ((fq * 16) ^ swz));
      bf16x8 kf1 = *(const bf16x8*)(kraw + n * 128 + ((64 + fq * 16) ^ swz));
      s[nb] = mfma16(kf0, qf0, s[nb]);
      s[nb] = mfma16(kf1, qf1, s[nb]);
    }
    __builtin_amdgcn_s_setprio(0);

    const u16* qn = qbase + (long)(((it + 1) & 7) * 128) * 512;
    bf16x8 qn0 = *(const bf16x8*)&qn[fq * 8];
    bf16x8 qn1 = *(const bf16x8*)&qn[32 + fq * 8];

    f32x4 mx = s[0];
    #pragma unroll
    for (int nb = 1; nb < 16; ++nb) {
      mx[0] = fmaxf(mx[0], s[nb][0]); mx[1] = fmaxf(mx[1], s[nb][1]);
      mx[2] = fmaxf(mx[2], s[nb][2]); mx[3] = fmaxf(mx[3], s[nb][3]);
    }
    float m = fmaxf(fmaxf(mx[0], mx[1]), fmaxf(mx[2], mx[3]));
    m = fmaxf(m, __shfl_xor(m, 16));
    m = fmaxf(m, __shfl_xor(m, 32));
    f32x4 sm = {0.f, 0.f, 0.f, 0.f};
    #pragma unroll
    for (int nb = 0; nb < 16; ++nb) {
      #pragma unroll
      for (int r = 0; r < 4; ++r)
        s[nb][r] = __builtin_amdgcn_exp2f(s[nb][r] - m);
      sm += s[nb];
    }
    float sum = (sm[0] + sm[1]) + (sm[2] + sm[3]);
    sum += __shfl_xor(sum, 16);
    sum += __shfl_xor(sum, 32);
    float inv = 1.0f / sum;

    #pragma unroll
    for (int nb = 0; nb < 16; ++nb) {
      bf16x4 pk;
      #pragma unroll
      for (int r = 0; r < 4; ++r) pk[r] = (__bf16)s[nb][r];
      *(bf16x4*)(praw + prowL * 512 + ((nb * 32 + fq * 8) ^ swz)) = pk;
    }
    asm volatile("s_waitcnt lgkmcnt(0)" ::: "memory");
    __builtin_amdgcn_sched_barrier(0);

    f32x4 o[4] = {};
    __builtin_amdgcn_s_setprio(1);
    #pragma unroll
    for (int kk2 = 0; kk2 < 8; ++kk2) {
      bf16x8 pf = *(const bf16x8*)(praw + prowL * 512 + ((kk2 * 64 + fq * 16) ^ swz));
      #pragma unroll
      for (int nfd = 0; nfd < 4; ++nfd) {
        bf16x8 vf = *(const bf16x8*)(vraw + (nfd * 16 + fr) * 512 +
                                     ((kk2 * 64 + fq * 16) ^ swz));
        o[nfd] = mfma16(vf, pf, o[nfd]);
      }
    }
    __builtin_amdgcn_s_setprio(0);

    u16* aob = ao + ((long)b * 4096 + p0 + it * 128 + w * 16 + fr) * 512 + h * 64;
    #pragma unroll
    for (int nfd = 0; nfd < 4; ++nfd) {
      bf16x4 ov;
      #pragma unroll
      for (int r = 0; r < 4; ++r) ov[r] = (__bf16)(o[nfd][r] * inv);
      *(bf16x4*)(aob + nfd * 16 + fq * 4) = ov;
    }
    qf0 = qn0;
    qf1 = qn1;
  }
}

// ---------------------------------------------------------------- launch
extern "C" void kernel_launch(void* const* d_in, const int* in_sizes, int n_in,
                              void* d_out, int out_size, void* d_ws, size_t ws_size,
                              hipStream_t stream) {
  const float* x    = (const float*)d_in[0];
  const float* ctx  = (const float*)d_in[1];
  const float* Wq   = (const float*)d_in[2];
  const float* Wkv  = (const float*)d_in[3];
  const float* Wout = (const float*)d_in[4];
  const float* bout = (const float*)d_in[5];
  float* out = (float*)d_out;
  char* ws = (char*)d_ws;

  u16* xT     = (u16*)(ws);              // 33,554,432 B (reused as ao)
  u16* q      = (u16*)(ws + 33554432);   // 33,554,432 B
  u16* kv     = (u16*)(ws + 67108864);   //  4,194,304 B
  u16* vT     = (u16*)(ws + 71303168);   //  2,097,152 B
  u16* Wq_b   = (u16*)(ws + 73400320);   //    524,288 B
  u16* Wkv_b  = (u16*)(ws + 73924608);   //  1,572,864 B
  u16* Wout_b = (u16*)(ws + 75497472);   //    524,288 B
  u16* ctx_b  = (u16*)(ws + 76021760);   //  3,145,728 B
  u16* ao     = xT;

  prep_cast<<<dim3(1024), dim3(256), 0, stream>>>(Wq, Wkv, Wout, ctx,
                                                  Wq_b, Wkv_b, Wout_b, ctx_b);
  transpose_x<<<dim3(64, 8, 8), dim3(256), 0, stream>>>(x, xT);
  // q[b][p][e] = sum_c xT[b][p][c] * (Wq*scale)[e][c]
  gemm_nt<0><<<dim3(32, 4, 8), dim3(256), 0, stream>>>(
      xT, Wq_b, (void*)q, 4096, 512, 512, 4096L * 512, 0L, 4096L * 512,
      nullptr, nullptr);
  // kv[bn][e2] = sum_c ctx[bn][c] * Wkv[e2][c]
  gemm_nt<0><<<dim3(16, 8, 1), dim3(256), 0, stream>>>(
      ctx_b, Wkv_b, (void*)kv, 2048, 1024, 768, 0L, 0L, 0L, nullptr, nullptr);
  transpose_v<<<dim3(8, 4, 8), dim3(256), 0, stream>>>(kv, vT);
  attn_kernel<<<dim3(4, 8, 8), dim3(512), 0, stream>>>(q, kv, vT, ao);
  // out[b][c][p] = sum_e Wout[c][e] * ao[b][p][e] + bout[c] + x[b][c][p]
  gemm_nt<1><<<dim3(4, 32, 8), dim3(256), 0, stream>>>(
      Wout_b, ao, (void*)out, 512, 4096, 512, 0L, 4096L * 512, 512L * 4096,
      bout, x);
}

// Round 7
// 141.205 us; speedup vs baseline: 1.2358x; 1.0184x over previous
//
#include <hip/hip_runtime.h>

typedef unsigned short u16;
typedef __bf16 bf16x8 __attribute__((ext_vector_type(8)));
typedef __bf16 bf16x4 __attribute__((ext_vector_type(4)));
typedef float f32x4 __attribute__((ext_vector_type(4)));

__device__ __forceinline__ u16 f2bf(float f) {
  __bf16 h = (__bf16)f;
  return *(u16*)&h;
}

__device__ __forceinline__ f32x4 mfma16(bf16x8 a, bf16x8 b, f32x4 c) {
  return __builtin_amdgcn_mfma_f32_16x16x32_bf16(a, b, c, 0, 0, 0);
}

__device__ __forceinline__ void async16(void* lds, const void* g) {
  __builtin_amdgcn_global_load_lds(
      (const __attribute__((address_space(1))) unsigned int*)g,
      (__attribute__((address_space(3))) unsigned int*)lds, 16, 0, 0);
}

// fold softmax scale AND log2(e) into Wq so softmax uses raw v_exp_f32 (exp2)
#define QSCALE 0.18033688011112042f  // 0.125 * log2(e)

// ---------------------------------------------------------------- prep: casts
__global__ __launch_bounds__(256) void prep_cast(
    const float* __restrict__ Wq, const float* __restrict__ Wkv,
    const float* __restrict__ Wout, const float* __restrict__ ctx,
    u16* __restrict__ Wq_b, u16* __restrict__ Wkv_b,
    u16* __restrict__ Wout_b, u16* __restrict__ ctx_b) {
  const long NWQ = 512L * 512, NWKV = 1024L * 768, NWOUT = 512L * 512, NCTX = 2048L * 768;
  const long total = NWQ + NWKV + NWOUT + NCTX;
  long stride = (long)gridDim.x * 256;
  for (long i = (long)blockIdx.x * 256 + threadIdx.x; i < total; i += stride) {
    long j = i;
    if (j < NWQ) { Wq_b[j] = f2bf(Wq[j] * QSCALE); continue; }
    j -= NWQ;
    if (j < NWKV) { Wkv_b[j] = f2bf(Wkv[j]); continue; }
    j -= NWKV;
    if (j < NWOUT) { Wout_b[j] = f2bf(Wout[j]); continue; }
    j -= NWOUT;
    ctx_b[j] = f2bf(ctx[j]);
  }
}

// ------------------------------------------------- transpose x -> xT bf16
__global__ __launch_bounds__(256) void transpose_x(const float* __restrict__ x,
                                                   u16* __restrict__ xT) {
  __shared__ float tile[64][65];
  const int b = blockIdx.z, p0 = blockIdx.x * 64, c0 = blockIdx.y * 64;
  const int tx = threadIdx.x & 63, ty = threadIdx.x >> 6;
  const float* xb = x + (long)b * (512L * 4096);
  #pragma unroll
  for (int i = ty; i < 64; i += 4)
    tile[i][tx] = xb[(long)(c0 + i) * 4096 + p0 + tx];
  __syncthreads();
  u16* xTb = xT + (long)b * (4096L * 512);
  #pragma unroll
  for (int i = ty; i < 64; i += 4)
    xTb[(long)(p0 + i) * 512 + c0 + tx] = f2bf(tile[tx][i]);
}

// ------------------------------------------------- transpose v -> vT bf16
__global__ __launch_bounds__(256) void transpose_v(const u16* __restrict__ kv,
                                                   u16* __restrict__ vT) {
  __shared__ u16 tile[64][65];
  const int b = blockIdx.z, e0 = blockIdx.x * 64, n0 = blockIdx.y * 64;
  const int tx = threadIdx.x & 63, ty = threadIdx.x >> 6;
  #pragma unroll
  for (int i = ty; i < 64; i += 4)
    tile[i][tx] = kv[(long)(b * 256 + n0 + i) * 1024 + 512 + e0 + tx];
  __syncthreads();
  #pragma unroll
  for (int i = ty; i < 64; i += 4)
    vT[(long)b * (512L * 256) + (long)(e0 + i) * 256 + n0 + tx] = tile[tx][i];
}

// ---------------------------------------------------------------- 128 GEMM
// kv-proj only (M=2048, N=1024, K=768).  128x128 tile, BK=64, dbuf
// global_load_lds, swizzled LDS.  bf16 store.
__global__ __launch_bounds__(256) void gemm_nt128(
    const u16* __restrict__ A, const u16* __restrict__ B, u16* __restrict__ C,
    int M, int N, int K) {
  __shared__ u16 ldsA[2][128 * 64];
  __shared__ u16 ldsB[2][128 * 64];
  const int t = threadIdx.x, wv = t >> 6, ln = t & 63;
  const int m0 = blockIdx.x * 128, n0 = blockIdx.y * 128;
  const int wr = wv >> 1, wc = wv & 1, fr = ln & 15, fq = ln >> 4;

  const u16* aSrc[4];
  const u16* bSrc[4];
  int lbase[4];
  #pragma unroll
  for (int i = 0; i < 4; i++) {
    int c = i * 256 + wv * 64 + ln;
    int row = c >> 3, slot = (c & 7) ^ (row & 7);
    aSrc[i] = A + (long)(m0 + row) * K + slot * 8;
    bSrc[i] = B + (long)(n0 + row) * K + slot * 8;
    lbase[i] = (i * 256 + wv * 64) * 8;
  }

  f32x4 acc[4][4] = {};
  const int nk = K >> 6;
  int cur = 0;

  #pragma unroll
  for (int i = 0; i < 4; i++) {
    async16(&ldsA[0][lbase[i]], aSrc[i]);
    async16(&ldsB[0][lbase[i]], bSrc[i]);
  }

  for (int kt = 0; kt < nk; ++kt) {
    __syncthreads();
    if (kt + 1 < nk) {
      const int ko = (kt + 1) * 64;
      #pragma unroll
      for (int i = 0; i < 4; i++) {
        async16(&ldsA[cur ^ 1][lbase[i]], aSrc[i] + ko);
        async16(&ldsB[cur ^ 1][lbase[i]], bSrc[i] + ko);
      }
    }
    const char* Ab = (const char*)ldsA[cur];
    const char* Bb = (const char*)ldsB[cur];
    #pragma unroll
    for (int kk = 0; kk < 2; ++kk) {
      bf16x8 a[4], b[4];
      #pragma unroll
      for (int mf = 0; mf < 4; ++mf) {
        int row = wr * 64 + mf * 16 + fr;
        a[mf] = *(const bf16x8*)(Ab + row * 128 +
                                 ((kk * 64 + fq * 16) ^ ((row & 7) << 4)));
      }
      #pragma unroll
      for (int nf = 0; nf < 4; ++nf) {
        int row = wc * 64 + nf * 16 + fr;
        b[nf] = *(const bf16x8*)(Bb + row * 128 +
                                 ((kk * 64 + fq * 16) ^ ((row & 7) << 4)));
      }
      #pragma unroll
      for (int mf = 0; mf < 4; ++mf)
        #pragma unroll
        for (int nf = 0; nf < 4; ++nf)
          acc[mf][nf] = mfma16(a[mf], b[nf], acc[mf][nf]);
    }
    cur ^= 1;
  }

  #pragma unroll
  for (int mf = 0; mf < 4; ++mf)
    #pragma unroll
    for (int r = 0; r < 4; ++r) {
      int grow = m0 + wr * 64 + mf * 16 + fq * 4 + r;
      #pragma unroll
      for (int nf = 0; nf < 4; ++nf) {
        int gcol = n0 + wc * 64 + nf * 16 + fr;
        C[(long)grow * N + gcol] = f2bf(acc[mf][nf][r]);
      }
    }
}

// ---------------------------------------------------------------- 256 GEMM
// The two big GEMMs.  256x256 tile, BK=64, 8 waves (2M x 4N, 128x64 each),
// same verified 2-phase sync skeleton (barrier -> stage-next -> ds_read ->
// MFMA), LDS 128 KB (1 block/CU), swizzled rows (2-way banks = free).
// EPI 0: bf16 store.  EPI 1: fp32 + bias[row] + resid (loads in epilogue).
template <int EPI>
__global__ __launch_bounds__(512, 2) void gemm_nt256(
    const u16* __restrict__ A, const u16* __restrict__ B, void* __restrict__ Cv,
    int M, int N, int K, long aStrideZ, long bStrideZ, long cStrideZ,
    const float* __restrict__ bias, const float* __restrict__ resid) {
  __shared__ u16 ldsA[2][256 * 64];   // 32 KB per buffer
  __shared__ u16 ldsB[2][256 * 64];
  const int t = threadIdx.x, wv = t >> 6, ln = t & 63;
  const int m0 = blockIdx.x * 256, n0 = blockIdx.y * 256, z = blockIdx.z;
  const u16* Az = A + (long)z * aStrideZ;
  const u16* Bz = B + (long)z * bStrideZ;
  const int wr = wv >> 2, wc = wv & 3, fr = ln & 15, fq = ln >> 4;

  // staging: 2048 chunks of 16B per array; chunk c -> row c>>3, slot c&7
  const u16* aSrc[4];
  const u16* bSrc[4];
  int lbase[4];
  #pragma unroll
  for (int i = 0; i < 4; i++) {
    int c = i * 512 + wv * 64 + ln;
    int row = c >> 3, slot = (c & 7) ^ (row & 7);   // inverse swizzle
    aSrc[i] = Az + (long)(m0 + row) * K + slot * 8;
    bSrc[i] = Bz + (long)(n0 + row) * K + slot * 8;
    lbase[i] = (i * 512 + wv * 64) * 8;             // u16 elems; HW adds lane*16B
  }

  f32x4 acc[8][4] = {};
  const int nk = K >> 6;
  int cur = 0;

  #pragma unroll
  for (int i = 0; i < 4; i++) {
    async16(&ldsA[0][lbase[i]], aSrc[i]);
    async16(&ldsB[0][lbase[i]], bSrc[i]);
  }

  for (int kt = 0; kt < nk; ++kt) {
    __syncthreads();   // compiler drains vmcnt/lgkmcnt before barrier
    if (kt + 1 < nk) {
      const int ko = (kt + 1) * 64;
      #pragma unroll
      for (int i = 0; i < 4; i++) {
        async16(&ldsA[cur ^ 1][lbase[i]], aSrc[i] + ko);
        async16(&ldsB[cur ^ 1][lbase[i]], bSrc[i] + ko);
      }
    }
    const char* Ab = (const char*)ldsA[cur];
    const char* Bb = (const char*)ldsB[cur];
    #pragma unroll
    for (int kk = 0; kk < 2; ++kk) {
      bf16x8 a[8], b[4];
      #pragma unroll
      for (int mf = 0; mf < 8; ++mf) {
        int row = wr * 128 + mf * 16 + fr;
        a[mf] = *(const bf16x8*)(Ab + row * 128 +
                                 ((kk * 64 + fq * 16) ^ ((row & 7) << 4)));
      }
      #pragma unroll
      for (int nf = 0; nf < 4; ++nf) {
        int row = wc * 64 + nf * 16 + fr;
        b[nf] = *(const bf16x8*)(Bb + row * 128 +
                                 ((kk * 64 + fq * 16) ^ ((row & 7) << 4)));
      }
      __builtin_amdgcn_s_setprio(1);
      #pragma unroll
      for (int mf = 0; mf < 8; ++mf)
        #pragma unroll
        for (int nf = 0; nf < 4; ++nf)
          acc[mf][nf] = mfma16(a[mf], b[nf], acc[mf][nf]);
      __builtin_amdgcn_s_setprio(0);
    }
    cur ^= 1;
  }

  if (EPI == 0) {
    u16* Cb = (u16*)Cv + (long)z * cStrideZ;
    #pragma unroll
    for (int mf = 0; mf < 8; ++mf)
      #pragma unroll
      for (int r = 0; r < 4; ++r) {
        int grow = m0 + wr * 128 + mf * 16 + fq * 4 + r;
        #pragma unroll
        for (int nf = 0; nf < 4; ++nf) {
          int gcol = n0 + wc * 64 + nf * 16 + fr;
          Cb[(long)grow * N + gcol] = f2bf(acc[mf][nf][r]);
        }
      }
  } else {
    float* Cf = (float*)Cv + (long)z * cStrideZ;
    const float* Rz = resid + (long)z * cStrideZ;
    #pragma unroll
    for (int mf = 0; mf < 8; ++mf)
      #pragma unroll
      for (int r = 0; r < 4; ++r) {
        int grow = m0 + wr * 128 + mf * 16 + fq * 4 + r;
        float bv = bias[grow];
        #pragma unroll
        for (int nf = 0; nf < 4; ++nf) {
          int gcol = n0 + wc * 64 + nf * 16 + fr;
          long idx = (long)grow * N + gcol;
          Cf[idx] = acc[mf][nf][r] + bv + Rz[idx];
        }
      }
  }
}

// ---------------------------------------------------------------- attention
// (round-5 structure, unchanged)
__global__ __launch_bounds__(512) void attn_kernel(
    const u16* __restrict__ q, const u16* __restrict__ kv,
    const u16* __restrict__ vT, u16* __restrict__ ao) {
  __shared__ u16 klds[256 * 64];
  __shared__ u16 vlds[64 * 256];
  __shared__ u16 plds[128 * 256];
  const int t = threadIdx.x, w = t >> 6, ln = t & 63;
  const int fr = ln & 15, fq = ln >> 4;
  const int p0 = blockIdx.x * 1024, h = blockIdx.y, b = blockIdx.z;

  const u16* kb = kv + (long)b * 256 * 1024 + h * 64;
  const u16* vb = vT + (long)b * (512L * 256) + (long)h * 64 * 256;

  #pragma unroll
  for (int i = 0; i < 4; ++i) {
    int cbase = i * 512 + w * 64;
    int chunk = cbase + ln;
    int row = chunk >> 3, slot = chunk & 7;
    async16(&klds[cbase * 8], kb + (long)row * 1024 + ((slot ^ (row & 7)) << 3));
  }
  #pragma unroll
  for (int i = 0; i < 4; ++i) {
    int cbase = i * 512 + w * 64;
    int chunk = cbase + ln;
    int row = chunk >> 5, slot = chunk & 31;
    async16(&vlds[cbase * 8], vb + (long)row * 256 + ((slot ^ (row & 7)) << 3));
  }
  __syncthreads();

  const char* kraw = (const char*)klds;
  const char* vraw = (const char*)vlds;
  char* praw = (char*)plds;
  const int prowL = w * 16 + fr;
  const int swz = (fr & 7) << 4;

  const u16* qbase = q + ((long)b * 4096 + p0 + w * 16 + fr) * 512 + h * 64;
  bf16x8 qf0 = *(const bf16x8*)&qbase[fq * 8];
  bf16x8 qf1 = *(const bf16x8*)&qbase[32 + fq * 8];

  for (int it = 0; it < 8; ++it) {
    f32x4 s[16] = {};
    __builtin_amdgcn_s_setprio(1);
    #pragma unroll
    for (int nb = 0; nb < 16; ++nb) {
      int n = nb * 16 + fr;
      bf16x8 kf0 = *(const bf16x8*)(kraw + n * 128 + ((fq * 16) ^ swz));
      bf16x8 kf1 = *(const bf16x8*)(kraw + n * 128 + ((64 + fq * 16) ^ swz));
      s[nb] = mfma16(kf0, qf0, s[nb]);
      s[nb] = mfma16(kf1, qf1, s[nb]);
    }
    __builtin_amdgcn_s_setprio(0);

    const u16* qn = qbase + (long)(((it + 1) & 7) * 128) * 512;
    bf16x8 qn0 = *(const bf16x8*)&qn[fq * 8];
    bf16x8 qn1 = *(const bf16x8*)&qn[32 + fq * 8];

    f32x4 mx = s[0];
    #pragma unroll
    for (int nb = 1; nb < 16; ++nb) {
      mx[0] = fmaxf(mx[0], s[nb][0]); mx[1] = fmaxf(mx[1], s[nb][1]);
      mx[2] = fmaxf(mx[2], s[nb][2]); mx[3] = fmaxf(mx[3], s[nb][3]);
    }
    float m = fmaxf(fmaxf(mx[0], mx[1]), fmaxf(mx[2], mx[3]));
    m = fmaxf(m, __shfl_xor(m, 16));
    m = fmaxf(m, __shfl_xor(m, 32));
    f32x4 sm = {0.f, 0.f, 0.f, 0.f};
    #pragma unroll
    for (int nb = 0; nb < 16; ++nb) {
      #pragma unroll
      for (int r = 0; r < 4; ++r)
        s[nb][r] = __builtin_amdgcn_exp2f(s[nb][r] - m);
      sm += s[nb];
    }
    float sum = (sm[0] + sm[1]) + (sm[2] + sm[3]);
    sum += __shfl_xor(sum, 16);
    sum += __shfl_xor(sum, 32);
    float inv = 1.0f / sum;

    #pragma unroll
    for (int nb = 0; nb < 16; ++nb) {
      bf16x4 pk;
      #pragma unroll
      for (int r = 0; r < 4; ++r) pk[r] = (__bf16)s[nb][r];
      *(bf16x4*)(praw + prowL * 512 + ((nb * 32 + fq * 8) ^ swz)) = pk;
    }
    asm volatile("s_waitcnt lgkmcnt(0)" ::: "memory");
    __builtin_amdgcn_sched_barrier(0);

    f32x4 o[4] = {};
    __builtin_amdgcn_s_setprio(1);
    #pragma unroll
    for (int kk2 = 0; kk2 < 8; ++kk2) {
      bf16x8 pf = *(const bf16x8*)(praw + prowL * 512 + ((kk2 * 64 + fq * 16) ^ swz));
      #pragma unroll
      for (int nfd = 0; nfd < 4; ++nfd) {
        bf16x8 vf = *(const bf16x8*)(vraw + (nfd * 16 + fr) * 512 +
                                     ((kk2 * 64 + fq * 16) ^ swz));
        o[nfd] = mfma16(vf, pf, o[nfd]);
      }
    }
    __builtin_amdgcn_s_setprio(0);

    u16* aob = ao + ((long)b * 4096 + p0 + it * 128 + w * 16 + fr) * 512 + h * 64;
    #pragma unroll
    for (int nfd = 0; nfd < 4; ++nfd) {
      bf16x4 ov;
      #pragma unroll
      for (int r = 0; r < 4; ++r) ov[r] = (__bf16)(o[nfd][r] * inv);
      *(bf16x4*)(aob + nfd * 16 + fq * 4) = ov;
    }
    qf0 = qn0;
    qf1 = qn1;
  }
}

// ---------------------------------------------------------------- launch
extern "C" void kernel_launch(void* const* d_in, const int* in_sizes, int n_in,
                              void* d_out, int out_size, void* d_ws, size_t ws_size,
                              hipStream_t stream) {
  const float* x    = (const float*)d_in[0];
  const float* ctx  = (const float*)d_in[1];
  const float* Wq   = (const float*)d_in[2];
  const float* Wkv  = (const float*)d_in[3];
  const float* Wout = (const float*)d_in[4];
  const float* bout = (const float*)d_in[5];
  float* out = (float*)d_out;
  char* ws = (char*)d_ws;

  u16* xT     = (u16*)(ws);              // 33,554,432 B (reused as ao)
  u16* q      = (u16*)(ws + 33554432);   // 33,554,432 B
  u16* kv     = (u16*)(ws + 67108864);   //  4,194,304 B
  u16* vT     = (u16*)(ws + 71303168);   //  2,097,152 B
  u16* Wq_b   = (u16*)(ws + 73400320);   //    524,288 B
  u16* Wkv_b  = (u16*)(ws + 73924608);   //  1,572,864 B
  u16* Wout_b = (u16*)(ws + 75497472);   //    524,288 B
  u16* ctx_b  = (u16*)(ws + 76021760);   //  3,145,728 B
  u16* ao     = xT;

  prep_cast<<<dim3(1024), dim3(256), 0, stream>>>(Wq, Wkv, Wout, ctx,
                                                  Wq_b, Wkv_b, Wout_b, ctx_b);
  transpose_x<<<dim3(64, 8, 8), dim3(256), 0, stream>>>(x, xT);
  // q[b][p][e] = sum_c xT[b][p][c] * (Wq*scale)[e][c]
  gemm_nt256<0><<<dim3(16, 2, 8), dim3(512), 0, stream>>>(
      xT, Wq_b, (void*)q, 4096, 512, 512, 4096L * 512, 0L, 4096L * 512,
      nullptr, nullptr);
  // kv[bn][e2] = sum_c ctx[bn][c] * Wkv[e2][c]
  gemm_nt128<<<dim3(16, 8, 1), dim3(256), 0, stream>>>(
      ctx_b, Wkv_b, kv, 2048, 1024, 768);
  transpose_v<<<dim3(8, 4, 8), dim3(256), 0, stream>>>(kv, vT);
  attn_kernel<<<dim3(4, 8, 8), dim3(512), 0, stream>>>(q, kv, vT, ao);
  // out[b][c][p] = sum_e Wout[c][e] * ao[b][p][e] + bout[c] + x[b][c][p]
  gemm_nt256<1><<<dim3(2, 16, 8), dim3(512), 0, stream>>>(
      Wout_b, ao, (void*)out, 512, 4096, 512, 0L, 4096L * 512, 512L * 4096,
      bout, x);
}

// Round 8
// 141.109 us; speedup vs baseline: 1.2367x; 1.0007x over previous
//
#include <hip/hip_runtime.h>

typedef unsigned short u16;
typedef __bf16 bf16x8 __attribute__((ext_vector_type(8)));
typedef __bf16 bf16x4 __attribute__((ext_vector_type(4)));
typedef float f32x4 __attribute__((ext_vector_type(4)));

__device__ __forceinline__ u16 f2bf(float f) {
  __bf16 h = (__bf16)f;
  return *(u16*)&h;
}

__device__ __forceinline__ f32x4 mfma16(bf16x8 a, bf16x8 b, f32x4 c) {
  return __builtin_amdgcn_mfma_f32_16x16x32_bf16(a, b, c, 0, 0, 0);
}

__device__ __forceinline__ void async16(void* lds, const void* g) {
  __builtin_amdgcn_global_load_lds(
      (const __attribute__((address_space(1))) unsigned int*)g,
      (__attribute__((address_space(3))) unsigned int*)lds, 16, 0, 0);
}

// fold softmax scale AND log2(e) into Wq so softmax uses raw v_exp_f32 (exp2)
#define QSCALE 0.18033688011112042f  // 0.125 * log2(e)

// ---------------------------------------------------------------- prep: casts
__global__ __launch_bounds__(256) void prep_cast(
    const float* __restrict__ Wq, const float* __restrict__ Wkv,
    const float* __restrict__ Wout, const float* __restrict__ ctx,
    u16* __restrict__ Wq_b, u16* __restrict__ Wkv_b,
    u16* __restrict__ Wout_b, u16* __restrict__ ctx_b) {
  const long NWQ = 512L * 512, NWKV = 1024L * 768, NWOUT = 512L * 512, NCTX = 2048L * 768;
  const long total = NWQ + NWKV + NWOUT + NCTX;
  long stride = (long)gridDim.x * 256;
  for (long i = (long)blockIdx.x * 256 + threadIdx.x; i < total; i += stride) {
    long j = i;
    if (j < NWQ) { Wq_b[j] = f2bf(Wq[j] * QSCALE); continue; }
    j -= NWQ;
    if (j < NWKV) { Wkv_b[j] = f2bf(Wkv[j]); continue; }
    j -= NWKV;
    if (j < NWOUT) { Wout_b[j] = f2bf(Wout[j]); continue; }
    j -= NWOUT;
    ctx_b[j] = f2bf(ctx[j]);
  }
}

// ------------------------------------------------- transpose x -> xT bf16
__global__ __launch_bounds__(256) void transpose_x(const float* __restrict__ x,
                                                   u16* __restrict__ xT) {
  __shared__ float tile[64][65];
  const int b = blockIdx.z, p0 = blockIdx.x * 64, c0 = blockIdx.y * 64;
  const int tx = threadIdx.x & 63, ty = threadIdx.x >> 6;
  const float* xb = x + (long)b * (512L * 4096);
  #pragma unroll
  for (int i = ty; i < 64; i += 4)
    tile[i][tx] = xb[(long)(c0 + i) * 4096 + p0 + tx];
  __syncthreads();
  u16* xTb = xT + (long)b * (4096L * 512);
  #pragma unroll
  for (int i = ty; i < 64; i += 4)
    xTb[(long)(p0 + i) * 512 + c0 + tx] = f2bf(tile[tx][i]);
}

// ------------------------------------------------- transpose v -> vT bf16
__global__ __launch_bounds__(256) void transpose_v(const u16* __restrict__ kv,
                                                   u16* __restrict__ vT) {
  __shared__ u16 tile[64][65];
  const int b = blockIdx.z, e0 = blockIdx.x * 64, n0 = blockIdx.y * 64;
  const int tx = threadIdx.x & 63, ty = threadIdx.x >> 6;
  #pragma unroll
  for (int i = ty; i < 64; i += 4)
    tile[i][tx] = kv[(long)(b * 256 + n0 + i) * 1024 + 512 + e0 + tx];
  __syncthreads();
  #pragma unroll
  for (int i = ty; i < 64; i += 4)
    vT[(long)b * (512L * 256) + (long)(e0 + i) * 256 + n0 + tx] = tile[tx][i];
}

// ---------------------------------------------------------------- 128 GEMM
// kv-proj only (M=2048, N=1024, K=768).  128x128 tile, BK=64, dbuf
// global_load_lds, swizzled LDS, __syncthreads skeleton (control kernel).
__global__ __launch_bounds__(256) void gemm_nt128(
    const u16* __restrict__ A, const u16* __restrict__ B, u16* __restrict__ C,
    int M, int N, int K) {
  __shared__ u16 ldsA[2][128 * 64];
  __shared__ u16 ldsB[2][128 * 64];
  const int t = threadIdx.x, wv = t >> 6, ln = t & 63;
  const int m0 = blockIdx.x * 128, n0 = blockIdx.y * 128;
  const int wr = wv >> 1, wc = wv & 1, fr = ln & 15, fq = ln >> 4;

  const u16* aSrc[4];
  const u16* bSrc[4];
  int lbase[4];
  #pragma unroll
  for (int i = 0; i < 4; i++) {
    int c = i * 256 + wv * 64 + ln;
    int row = c >> 3, slot = (c & 7) ^ (row & 7);
    aSrc[i] = A + (long)(m0 + row) * K + slot * 8;
    bSrc[i] = B + (long)(n0 + row) * K + slot * 8;
    lbase[i] = (i * 256 + wv * 64) * 8;
  }

  f32x4 acc[4][4] = {};
  const int nk = K >> 6;
  int cur = 0;

  #pragma unroll
  for (int i = 0; i < 4; i++) {
    async16(&ldsA[0][lbase[i]], aSrc[i]);
    async16(&ldsB[0][lbase[i]], bSrc[i]);
  }

  for (int kt = 0; kt < nk; ++kt) {
    __syncthreads();
    if (kt + 1 < nk) {
      const int ko = (kt + 1) * 64;
      #pragma unroll
      for (int i = 0; i < 4; i++) {
        async16(&ldsA[cur ^ 1][lbase[i]], aSrc[i] + ko);
        async16(&ldsB[cur ^ 1][lbase[i]], bSrc[i] + ko);
      }
    }
    const char* Ab = (const char*)ldsA[cur];
    const char* Bb = (const char*)ldsB[cur];
    #pragma unroll
    for (int kk = 0; kk < 2; ++kk) {
      bf16x8 a[4], b[4];
      #pragma unroll
      for (int mf = 0; mf < 4; ++mf) {
        int row = wr * 64 + mf * 16 + fr;
        a[mf] = *(const bf16x8*)(Ab + row * 128 +
                                 ((kk * 64 + fq * 16) ^ ((row & 7) << 4)));
      }
      #pragma unroll
      for (int nf = 0; nf < 4; ++nf) {
        int row = wc * 64 + nf * 16 + fr;
        b[nf] = *(const bf16x8*)(Bb + row * 128 +
                                 ((kk * 64 + fq * 16) ^ ((row & 7) << 4)));
      }
      #pragma unroll
      for (int mf = 0; mf < 4; ++mf)
        #pragma unroll
        for (int nf = 0; nf < 4; ++nf)
          acc[mf][nf] = mfma16(a[mf], b[nf], acc[mf][nf]);
    }
    cur ^= 1;
  }

  #pragma unroll
  for (int mf = 0; mf < 4; ++mf)
    #pragma unroll
    for (int r = 0; r < 4; ++r) {
      int grow = m0 + wr * 64 + mf * 16 + fq * 4 + r;
      #pragma unroll
      for (int nf = 0; nf < 4; ++nf) {
        int gcol = n0 + wc * 64 + nf * 16 + fr;
        C[(long)grow * N + gcol] = f2bf(acc[mf][nf][r]);
      }
    }
}

// ---------------------------------------------------------------- 256 GEMM
// The two big GEMMs.  256x256 tile, BK=64, 8 waves (2M x 4N).
// T4 counted-vmcnt schedule: raw s_barrier pairs, next-tile global_load_lds
// stays in flight (vmcnt(8)) THROUGH the MFMA phase — never drain-0 in loop.
// Race safety: per-wave vmcnt(8) before barrier-1 => all waves' current-buf
// loads landed; barrier-2 after MFMA (ds_reads retired via operand waits)
// => no wave re-stages a buffer still being read.
// EPI 0: bf16 store.  EPI 1: fp32 + bias[row] + resid (loads in epilogue).
template <int EPI>
__global__ __launch_bounds__(512, 2) void gemm_nt256(
    const u16* __restrict__ A, const u16* __restrict__ B, void* __restrict__ Cv,
    int M, int N, int K, long aStrideZ, long bStrideZ, long cStrideZ,
    const float* __restrict__ bias, const float* __restrict__ resid) {
  __shared__ u16 ldsA[2][256 * 64];   // 32 KB per buffer
  __shared__ u16 ldsB[2][256 * 64];
  const int t = threadIdx.x, wv = t >> 6, ln = t & 63;
  const int m0 = blockIdx.x * 256, n0 = blockIdx.y * 256, z = blockIdx.z;
  const u16* Az = A + (long)z * aStrideZ;
  const u16* Bz = B + (long)z * bStrideZ;
  const int wr = wv >> 2, wc = wv & 3, fr = ln & 15, fq = ln >> 4;

  // staging: 2048 chunks of 16B per array; chunk c -> row c>>3, slot c&7
  const u16* aSrc[4];
  const u16* bSrc[4];
  int lbase[4];
  #pragma unroll
  for (int i = 0; i < 4; i++) {
    int c = i * 512 + wv * 64 + ln;
    int row = c >> 3, slot = (c & 7) ^ (row & 7);   // inverse swizzle
    aSrc[i] = Az + (long)(m0 + row) * K + slot * 8;
    bSrc[i] = Bz + (long)(n0 + row) * K + slot * 8;
    lbase[i] = (i * 512 + wv * 64) * 8;             // u16 elems; HW adds lane*16B
  }

  f32x4 acc[8][4] = {};
  const int nk = K >> 6;
  int cur = 0;

  // prologue: stage K-tile 0 into buffer 0 (8 loads in flight)
  #pragma unroll
  for (int i = 0; i < 4; i++) {
    async16(&ldsA[0][lbase[i]], aSrc[i]);
    async16(&ldsB[0][lbase[i]], bSrc[i]);
  }

  for (int kt = 0; kt < nk; ++kt) {
    if (kt + 1 < nk) {
      const int ko = (kt + 1) * 64;
      #pragma unroll
      for (int i = 0; i < 4; i++) {
        async16(&ldsA[cur ^ 1][lbase[i]], aSrc[i] + ko);
        async16(&ldsB[cur ^ 1][lbase[i]], bSrc[i] + ko);
      }
      // my current-buffer loads (oldest 8) landed; next-tile 8 stay in flight
      asm volatile("s_waitcnt vmcnt(8)" ::: "memory");
    } else {
      asm volatile("s_waitcnt vmcnt(0)" ::: "memory");
    }
    __builtin_amdgcn_s_barrier();
    __builtin_amdgcn_sched_barrier(0);   // nothing hoists above the barrier

    const char* Ab = (const char*)ldsA[cur];
    const char* Bb = (const char*)ldsB[cur];
    #pragma unroll
    for (int kk = 0; kk < 2; ++kk) {
      bf16x8 a[8], b[4];
      #pragma unroll
      for (int mf = 0; mf < 8; ++mf) {
        int row = wr * 128 + mf * 16 + fr;
        a[mf] = *(const bf16x8*)(Ab + row * 128 +
                                 ((kk * 64 + fq * 16) ^ ((row & 7) << 4)));
      }
      #pragma unroll
      for (int nf = 0; nf < 4; ++nf) {
        int row = wc * 64 + nf * 16 + fr;
        b[nf] = *(const bf16x8*)(Bb + row * 128 +
                                 ((kk * 64 + fq * 16) ^ ((row & 7) << 4)));
      }
      __builtin_amdgcn_s_setprio(1);
      #pragma unroll
      for (int mf = 0; mf < 8; ++mf)
        #pragma unroll
        for (int nf = 0; nf < 4; ++nf)
          acc[mf][nf] = mfma16(a[mf], b[nf], acc[mf][nf]);
      __builtin_amdgcn_s_setprio(0);
    }

    __builtin_amdgcn_sched_barrier(0);   // nothing sinks below into next stage
    __builtin_amdgcn_s_barrier();        // all reads of buf[cur] retired
    cur ^= 1;
  }

  if (EPI == 0) {
    u16* Cb = (u16*)Cv + (long)z * cStrideZ;
    #pragma unroll
    for (int mf = 0; mf < 8; ++mf)
      #pragma unroll
      for (int r = 0; r < 4; ++r) {
        int grow = m0 + wr * 128 + mf * 16 + fq * 4 + r;
        #pragma unroll
        for (int nf = 0; nf < 4; ++nf) {
          int gcol = n0 + wc * 64 + nf * 16 + fr;
          Cb[(long)grow * N + gcol] = f2bf(acc[mf][nf][r]);
        }
      }
  } else {
    float* Cf = (float*)Cv + (long)z * cStrideZ;
    const float* Rz = resid + (long)z * cStrideZ;
    #pragma unroll
    for (int mf = 0; mf < 8; ++mf)
      #pragma unroll
      for (int r = 0; r < 4; ++r) {
        int grow = m0 + wr * 128 + mf * 16 + fq * 4 + r;
        float bv = bias[grow];
        #pragma unroll
        for (int nf = 0; nf < 4; ++nf) {
          int gcol = n0 + wc * 64 + nf * 16 + fr;
          long idx = (long)grow * N + gcol;
          Cf[idx] = acc[mf][nf][r] + bv + Rz[idx];
        }
      }
  }
}

// ---------------------------------------------------------------- attention
// (round-5 structure, unchanged)
__global__ __launch_bounds__(512) void attn_kernel(
    const u16* __restrict__ q, const u16* __restrict__ kv,
    const u16* __restrict__ vT, u16* __restrict__ ao) {
  __shared__ u16 klds[256 * 64];
  __shared__ u16 vlds[64 * 256];
  __shared__ u16 plds[128 * 256];
  const int t = threadIdx.x, w = t >> 6, ln = t & 63;
  const int fr = ln & 15, fq = ln >> 4;
  const int p0 = blockIdx.x * 1024, h = blockIdx.y, b = blockIdx.z;

  const u16* kb = kv + (long)b * 256 * 1024 + h * 64;
  const u16* vb = vT + (long)b * (512L * 256) + (long)h * 64 * 256;

  #pragma unroll
  for (int i = 0; i < 4; ++i) {
    int cbase = i * 512 + w * 64;
    int chunk = cbase + ln;
    int row = chunk >> 3, slot = chunk & 7;
    async16(&klds[cbase * 8], kb + (long)row * 1024 + ((slot ^ (row & 7)) << 3));
  }
  #pragma unroll
  for (int i = 0; i < 4; ++i) {
    int cbase = i * 512 + w * 64;
    int chunk = cbase + ln;
    int row = chunk >> 5, slot = chunk & 31;
    async16(&vlds[cbase * 8], vb + (long)row * 256 + ((slot ^ (row & 7)) << 3));
  }
  __syncthreads();

  const char* kraw = (const char*)klds;
  const char* vraw = (const char*)vlds;
  char* praw = (char*)plds;
  const int prowL = w * 16 + fr;
  const int swz = (fr & 7) << 4;

  const u16* qbase = q + ((long)b * 4096 + p0 + w * 16 + fr) * 512 + h * 64;
  bf16x8 qf0 = *(const bf16x8*)&qbase[fq * 8];
  bf16x8 qf1 = *(const bf16x8*)&qbase[32 + fq * 8];

  for (int it = 0; it < 8; ++it) {
    f32x4 s[16] = {};
    __builtin_amdgcn_s_setprio(1);
    #pragma unroll
    for (int nb = 0; nb < 16; ++nb) {
      int n = nb * 16 + fr;
      bf16x8 kf0 = *(const bf16x8*)(kraw + n * 128 + ((fq * 16) ^ swz));
      bf16x8 kf1 = *(const bf16x8*)(kraw + n * 128 + ((64 + fq * 16) ^ swz));
      s[nb] = mfma16(kf0, qf0, s[nb]);
      s[nb] = mfma16(kf1, qf1, s[nb]);
    }
    __builtin_amdgcn_s_setprio(0);

    const u16* qn = qbase + (long)(((it + 1) & 7) * 128) * 512;
    bf16x8 qn0 = *(const bf16x8*)&qn[fq * 8];
    bf16x8 qn1 = *(const bf16x8*)&qn[32 + fq * 8];

    f32x4 mx = s[0];
    #pragma unroll
    for (int nb = 1; nb < 16; ++nb) {
      mx[0] = fmaxf(mx[0], s[nb][0]); mx[1] = fmaxf(mx[1], s[nb][1]);
      mx[2] = fmaxf(mx[2], s[nb][2]); mx[3] = fmaxf(mx[3], s[nb][3]);
    }
    float m = fmaxf(fmaxf(mx[0], mx[1]), fmaxf(mx[2], mx[3]));
    m = fmaxf(m, __shfl_xor(m, 16));
    m = fmaxf(m, __shfl_xor(m, 32));
    f32x4 sm = {0.f, 0.f, 0.f, 0.f};
    #pragma unroll
    for (int nb = 0; nb < 16; ++nb) {
      #pragma unroll
      for (int r = 0; r < 4; ++r)
        s[nb][r] = __builtin_amdgcn_exp2f(s[nb][r] - m);
      sm += s[nb];
    }
    float sum = (sm[0] + sm[1]) + (sm[2] + sm[3]);
    sum += __shfl_xor(sum, 16);
    sum += __shfl_xor(sum, 32);
    float inv = 1.0f / sum;

    #pragma unroll
    for (int nb = 0; nb < 16; ++nb) {
      bf16x4 pk;
      #pragma unroll
      for (int r = 0; r < 4; ++r) pk[r] = (__bf16)s[nb][r];
      *(bf16x4*)(praw + prowL * 512 + ((nb * 32 + fq * 8) ^ swz)) = pk;
    }
    asm volatile("s_waitcnt lgkmcnt(0)" ::: "memory");
    __builtin_amdgcn_sched_barrier(0);

    f32x4 o[4] = {};
    __builtin_amdgcn_s_setprio(1);
    #pragma unroll
    for (int kk2 = 0; kk2 < 8; ++kk2) {
      bf16x8 pf = *(const bf16x8*)(praw + prowL * 512 + ((kk2 * 64 + fq * 16) ^ swz));
      #pragma unroll
      for (int nfd = 0; nfd < 4; ++nfd) {
        bf16x8 vf = *(const bf16x8*)(vraw + (nfd * 16 + fr) * 512 +
                                     ((kk2 * 64 + fq * 16) ^ swz));
        o[nfd] = mfma16(vf, pf, o[nfd]);
      }
    }
    __builtin_amdgcn_s_setprio(0);

    u16* aob = ao + ((long)b * 4096 + p0 + it * 128 + w * 16 + fr) * 512 + h * 64;
    #pragma unroll
    for (int nfd = 0; nfd < 4; ++nfd) {
      bf16x4 ov;
      #pragma unroll
      for (int r = 0; r < 4; ++r) ov[r] = (__bf16)(o[nfd][r] * inv);
      *(bf16x4*)(aob + nfd * 16 + fq * 4) = ov;
    }
    qf0 = qn0;
    qf1 = qn1;
  }
}

// ---------------------------------------------------------------- launch
extern "C" void kernel_launch(void* const* d_in, const int* in_sizes, int n_in,
                              void* d_out, int out_size, void* d_ws, size_t ws_size,
                              hipStream_t stream) {
  const float* x    = (const float*)d_in[0];
  const float* ctx  = (const float*)d_in[1];
  const float* Wq   = (const float*)d_in[2];
  const float* Wkv  = (const float*)d_in[3];
  const float* Wout = (const float*)d_in[4];
  const float* bout = (const float*)d_in[5];
  float* out = (float*)d_out;
  char* ws = (char*)d_ws;

  u16* xT     = (u16*)(ws);              // 33,554,432 B (reused as ao)
  u16* q      = (u16*)(ws + 33554432);   // 33,554,432 B
  u16* kv     = (u16*)(ws + 67108864);   //  4,194,304 B
  u16* vT     = (u16*)(ws + 71303168);   //  2,097,152 B
  u16* Wq_b   = (u16*)(ws + 73400320);   //    524,288 B
  u16* Wkv_b  = (u16*)(ws + 73924608);   //  1,572,864 B
  u16* Wout_b = (u16*)(ws + 75497472);   //    524,288 B
  u16* ctx_b  = (u16*)(ws + 76021760);   //  3,145,728 B
  u16* ao     = xT;

  prep_cast<<<dim3(1024), dim3(256), 0, stream>>>(Wq, Wkv, Wout, ctx,
                                                  Wq_b, Wkv_b, Wout_b, ctx_b);
  transpose_x<<<dim3(64, 8, 8), dim3(256), 0, stream>>>(x, xT);
  // q[b][p][e] = sum_c xT[b][p][c] * (Wq*scale)[e][c]
  gemm_nt256<0><<<dim3(16, 2, 8), dim3(512), 0, stream>>>(
      xT, Wq_b, (void*)q, 4096, 512, 512, 4096L * 512, 0L, 4096L * 512,
      nullptr, nullptr);
  // kv[bn][e2] = sum_c ctx[bn][c] * Wkv[e2][c]
  gemm_nt128<<<dim3(16, 8, 1), dim3(256), 0, stream>>>(
      ctx_b, Wkv_b, kv, 2048, 1024, 768);
  transpose_v<<<dim3(8, 4, 8), dim3(256), 0, stream>>>(kv, vT);
  attn_kernel<<<dim3(4, 8, 8), dim3(512), 0, stream>>>(q, kv, vT, ao);
  // out[b][c][p] = sum_e Wout[c][e] * ao[b][p][e] + bout[c] + x[b][c][p]
  gemm_nt256<1><<<dim3(2, 16, 8), dim3(512), 0, stream>>>(
      Wout_b, ao, (void*)out, 512, 4096, 512, 0L, 4096L * 512, 512L * 4096,
      bout, x);
}